// Round 3
// baseline (322.039 us; speedup 1.0000x reference)
//
#include <hip/hip_runtime.h>
#include <stdint.h>

typedef unsigned short ushort_t;
typedef __attribute__((ext_vector_type(8))) short short8;
typedef __attribute__((ext_vector_type(8))) _Float16 half8;
typedef __attribute__((ext_vector_type(4))) float f32x4;
typedef __attribute__((ext_vector_type(4))) unsigned short us4;

#define AS1 __attribute__((address_space(1)))
#define AS3 __attribute__((address_space(3)))

#if __has_builtin(__builtin_amdgcn_exp2f)
#define EXP2(x) __builtin_amdgcn_exp2f(x)
#else
#define EXP2(x) exp2f(x)
#endif

// scores are multiplied by 8 (the reference's /scale bug); fold into exp2 base
#define SC 11.541560327111707f  // 8 * log2(e)

__device__ __forceinline__ ushort_t f2h(float f) {
  _Float16 h = (_Float16)f;   // v_cvt_f16_f32, RNE
  return __builtin_bit_cast(unsigned short, h);
}

__device__ __forceinline__ void gload16(const void* g, void* l) {
  __builtin_amdgcn_global_load_lds((AS1 const void*)g, (AS3 void*)l, 16, 0, 0);
}

__device__ __forceinline__ f32x4 mfma16(short8 a, short8 b, f32x4 c) {
  return __builtin_amdgcn_mfma_f32_16x16x32_f16(
      __builtin_bit_cast(half8, a), __builtin_bit_cast(half8, b), c, 0, 0, 0);
}

// ---------------- cast x fp32 -> fp16 ----------------
__global__ __launch_bounds__(256) void cast_f32_f16(const float4* __restrict__ in,
                                                    us4* __restrict__ out, int n4) {
  int i = blockIdx.x * 256 + threadIdx.x;
  int stride = gridDim.x * 256;
  for (; i < n4; i += stride) {
    float4 v = in[i];
    us4 o;
    o[0] = f2h(v.x); o[1] = f2h(v.y); o[2] = f2h(v.z); o[3] = f2h(v.w);
    out[i] = o;
  }
}

// ---------------- transpose-cast W [R][C] fp32 -> Wt [C][R] fp16 ----------------
__global__ __launch_bounds__(256) void tcast(const float* __restrict__ in,
                                             ushort_t* __restrict__ out, int R, int C) {
  __shared__ __align__(16) float lt[32][33];
  const int r0 = blockIdx.y * 32, c0 = blockIdx.x * 32;
  const int i = threadIdx.x;
  const int lr = i >> 3, lc = (i & 7) * 4;
  float4 v = *(const float4*)(in + (size_t)(r0 + lr) * C + c0 + lc);
  lt[lr][lc + 0] = v.x; lt[lr][lc + 1] = v.y; lt[lr][lc + 2] = v.z; lt[lr][lc + 3] = v.w;
  __syncthreads();
  const int oc = i >> 3;          // out row (a column c of in)
  const int orr = (i & 7) * 4;    // out col (row r of in)
  us4 o;
#pragma unroll
  for (int jj = 0; jj < 4; ++jj) o[jj] = f2h(lt[orr + jj][oc]);
  *(us4*)(out + (size_t)(c0 + oc) * R + r0 + orr) = o;
}

// ---------------- 128x128 fp16 GEMM, BK=64, A[M][K] x Bt[N][K] ----------------
// MODE 0: epilogue scatters into q/k/v head layouts (fp16)
// MODE 1: epilogue writes fp32 out[M][N]
template<int MODE>
__global__ __launch_bounds__(256) void gemm128(
    const ushort_t* __restrict__ A, const ushort_t* __restrict__ Bt, int K, int N,
    ushort_t* __restrict__ qo, ushort_t* __restrict__ ko, ushort_t* __restrict__ vo,
    float* __restrict__ outp)
{
  __shared__ __align__(16) unsigned char lds[32768];   // A tile 16K, B tile 16K
  const int tid = threadIdx.x;
  const int lane = tid & 63, w = tid >> 6;
  const int ln = lane & 15, gq = lane >> 4;
  const int wr = w >> 1, wc = w & 1;
  const int m0 = blockIdx.y * 128, n0 = blockIdx.x * 128;
  const size_t ldb = (size_t)K * 2;  // row bytes
  const unsigned char* ab = (const unsigned char*)A + (size_t)m0 * ldb;
  const unsigned char* bb = (const unsigned char*)Bt + (size_t)n0 * ldb;
  f32x4 acc[4][4] = {};
  const int nkt = K >> 6;
  for (int kb = 0; kb < nkt; ++kb) {
    const unsigned char* abk = ab + kb * 128;
    const unsigned char* bbk = bb + kb * 128;
#pragma unroll
    for (int e = 0; e < 4; ++e) {
      unsigned o = e * 4096 + tid * 16;
      unsigned r = o >> 7;
      unsigned c = (o & 127) ^ ((r & 7) << 4);   // pre-swizzled source
      gload16(abk + (size_t)r * ldb + c, lds + o);
      gload16(bbk + (size_t)r * ldb + c, lds + 16384 + o);
    }
    __syncthreads();
    short8 af[4][2], bf8[4][2];
#pragma unroll
    for (int mi = 0; mi < 4; ++mi) {
      unsigned row = wr * 64 + mi * 16 + ln;
      unsigned c0 = (gq * 16) ^ ((row & 7) << 4);
      af[mi][0] = *(const short8*)(lds + row * 128 + c0);
      af[mi][1] = *(const short8*)(lds + row * 128 + (c0 ^ 64));
    }
#pragma unroll
    for (int ni = 0; ni < 4; ++ni) {
      unsigned row = wc * 64 + ni * 16 + ln;
      unsigned c0 = (gq * 16) ^ ((row & 7) << 4);
      bf8[ni][0] = *(const short8*)(lds + 16384 + row * 128 + c0);
      bf8[ni][1] = *(const short8*)(lds + 16384 + row * 128 + (c0 ^ 64));
    }
#pragma unroll
    for (int mi = 0; mi < 4; ++mi)
#pragma unroll
      for (int ni = 0; ni < 4; ++ni) {
        acc[mi][ni] = mfma16(af[mi][0], bf8[ni][0], acc[mi][ni]);
        acc[mi][ni] = mfma16(af[mi][1], bf8[ni][1], acc[mi][ni]);
      }
    __syncthreads();
  }
  // epilogue: D layout col = lane&15, row = (lane>>4)*4 + j
  if (MODE == 0) {
#pragma unroll
    for (int mi = 0; mi < 4; ++mi)
#pragma unroll
      for (int ni = 0; ni < 4; ++ni)
#pragma unroll
        for (int j = 0; j < 4; ++j) {
          int token = m0 + wr * 64 + mi * 16 + gq * 4 + j;
          int feat  = n0 + wc * 64 + ni * 16 + ln;
          int sec = feat >> 10, cc = feat & 1023;
          int hh = cc >> 6, dd = cc & 63;
          size_t off = (((size_t)(token >> 11) * 16 + hh) * 2048 + (token & 2047)) * 64 + dd;
          ushort_t valb = f2h(acc[mi][ni][j]);
          if (sec == 0) qo[off] = valb;
          else if (sec == 1) ko[off] = valb;
          else vo[off] = valb;
        }
  } else {
#pragma unroll
    for (int mi = 0; mi < 4; ++mi)
#pragma unroll
      for (int ni = 0; ni < 4; ++ni)
#pragma unroll
        for (int j = 0; j < 4; ++j) {
          int token = m0 + wr * 64 + mi * 16 + gq * 4 + j;
          int feat  = n0 + wc * 64 + ni * 16 + ln;
          outp[(size_t)token * N + feat] = acc[mi][ni][j];
        }
  }
}

// ---------------- V [bh][2048][64] -> Vt [bh][64][2048] ----------------
__global__ __launch_bounds__(256) void transpose_v(const ushort_t* __restrict__ vn,
                                                   ushort_t* __restrict__ vt) {
  __shared__ __align__(16) ushort_t lt[64][80];
  const int bh = blockIdx.y, t0 = blockIdx.x * 64;
  const int i = threadIdx.x;
  {
    const int tr = i >> 2, dc = (i & 3) * 16;
    const ushort_t* src = vn + ((size_t)bh * 2048 + t0 + tr) * 64 + dc;
    *(short8*)&lt[tr][dc] = *(const short8*)src;
    *(short8*)&lt[tr][dc + 8] = *(const short8*)(src + 8);
  }
  __syncthreads();
  {
    const int dr = i >> 2, tc = (i & 3) * 16;
    short8 a, b;
#pragma unroll
    for (int jj = 0; jj < 8; ++jj) a[jj] = (short)lt[tc + jj][dr];
#pragma unroll
    for (int jj = 0; jj < 8; ++jj) b[jj] = (short)lt[tc + 8 + jj][dr];
    ushort_t* dst = vt + ((size_t)bh * 64 + dr) * 2048 + t0 + tc;
    *(short8*)dst = a;
    *(short8*)(dst + 8) = b;
  }
}

// ---------------- flash attention: block = (qb, bh), 4 waves x 32 q-rows, QBLK=128 ----------------
// LDS: K dbuf @0/8192, Vt dbuf @16384/24576, P per-wave @32768 + w*4096  (total 48KB)
__global__ __launch_bounds__(256) void attn_kernel(const ushort_t* __restrict__ qg,
                                                   const ushort_t* __restrict__ kg,
                                                   const ushort_t* __restrict__ vtg,
                                                   ushort_t* __restrict__ yg) {
  __shared__ __align__(16) unsigned char lds[49152];
  const int qb = 15 - blockIdx.x;    // longest blocks first
  const int bh = blockIdx.y;         // 0..63
  const int tid = threadIdx.x;
  const int lane = tid & 63, w = tid >> 6;
  const int ln = lane & 15, gq = lane >> 4;
  const int q0 = qb * 128;
  const int nt = 2 * qb + 2;         // KV tiles of 64

  // Q fragments (A-operand): row = lane&15, k = gq*8 + j (+32 for second k-step)
  const ushort_t* qrow = qg + ((size_t)bh * 2048 + q0 + w * 32 + ln) * 64;
  short8 qa[2][2];
  qa[0][0] = *(const short8*)(qrow + gq * 8);
  qa[0][1] = *(const short8*)(qrow + 32 + gq * 8);
  qa[1][0] = *(const short8*)(qrow + 16 * 64 + gq * 8);
  qa[1][1] = *(const short8*)(qrow + 16 * 64 + 32 + gq * 8);

  f32x4 yacc[2][4] = {};
  float mrow[2][4], lrow[2][4];
#pragma unroll
  for (int qf = 0; qf < 2; ++qf)
#pragma unroll
    for (int j = 0; j < 4; ++j) { mrow[qf][j] = -3e38f; lrow[qf][j] = 0.f; }

  const unsigned char* kbase = (const unsigned char*)kg + (size_t)bh * 2048 * 128;
  const unsigned char* vbase = (const unsigned char*)vtg + (size_t)bh * 64 * 4096;

  // stage tile t into buffer buf (K: 8KB contiguous; Vt: 64 rows x 128B, row stride 4KB)
  auto stage = [&](int buf, int t) {
    const unsigned char* kt = kbase + (size_t)t * 8192;
    const unsigned char* vt = vbase + t * 128;
#pragma unroll
    for (int e = 0; e < 2; ++e) {
      unsigned o = e * 4096 + tid * 16;
      unsigned r = o >> 7;
      unsigned c = (o & 127) ^ ((r & 7) << 4);
      gload16(kt + r * 128 + c, lds + buf * 8192 + o);
      gload16(vt + (size_t)r * 4096 + c, lds + 16384 + buf * 8192 + o);
    }
  };

  stage(0, 0);
  __syncthreads();

  for (int t = 0; t < nt; ++t) {
    const int buf = t & 1;
    if (t + 1 < nt) stage(buf ^ 1, t + 1);   // prefetch next tile (other buffer)
    const int kv0 = t * 64;
    // last tile (kv0 = q0+64): waves 0,1 are fully masked -> skip compute
    const bool active_wave = (w * 32 + 31) >= (kv0 - q0);
    if (active_wave) {
      const unsigned kb_ = buf * 8192;
      const unsigned vb_ = 16384 + buf * 8192;
      const unsigned pw = 32768 + w * 4096;
      // QK^T: S[32 q][64 kv] in 2x4 fragments
      f32x4 s[2][4];
#pragma unroll
      for (int f = 0; f < 4; ++f) {
        unsigned row = f * 16 + ln;
        unsigned c0 = (gq * 16) ^ ((row & 7) << 4);
        short8 k0 = *(const short8*)(lds + kb_ + row * 128 + c0);
        short8 k1 = *(const short8*)(lds + kb_ + row * 128 + (c0 ^ 64));
#pragma unroll
        for (int qf = 0; qf < 2; ++qf) {
          f32x4 z = {0.f, 0.f, 0.f, 0.f};
          z = mfma16(qa[qf][0], k0, z);
          s[qf][f] = mfma16(qa[qf][1], k1, z);
        }
      }
      if (t >= nt - 2) {   // diagonal tiles: mask kv > q
#pragma unroll
        for (int qf = 0; qf < 2; ++qf)
#pragma unroll
          for (int f = 0; f < 4; ++f) {
            int kvg = kv0 + f * 16 + ln;
#pragma unroll
            for (int j = 0; j < 4; ++j) {
              int qg_ = q0 + w * 32 + qf * 16 + gq * 4 + j;
              if (kvg > qg_) s[qf][f][j] = -3e38f;
            }
          }
      }
      // online softmax (row = 16 lanes of group gq; col = ln)
#pragma unroll
      for (int qf = 0; qf < 2; ++qf)
#pragma unroll
        for (int j = 0; j < 4; ++j) {
          float rm = fmaxf(fmaxf(s[qf][0][j], s[qf][1][j]), fmaxf(s[qf][2][j], s[qf][3][j]));
          rm = fmaxf(rm, __shfl_xor(rm, 1));
          rm = fmaxf(rm, __shfl_xor(rm, 2));
          rm = fmaxf(rm, __shfl_xor(rm, 4));
          rm = fmaxf(rm, __shfl_xor(rm, 8));
          float mnew = fmaxf(mrow[qf][j], rm);
          float alpha = EXP2((mrow[qf][j] - mnew) * SC);
          float rs = 0.f;
#pragma unroll
          for (int f = 0; f < 4; ++f) {
            float p = EXP2((s[qf][f][j] - mnew) * SC);
            s[qf][f][j] = p;
            rs += p;
          }
          rs += __shfl_xor(rs, 1);
          rs += __shfl_xor(rs, 2);
          rs += __shfl_xor(rs, 4);
          rs += __shfl_xor(rs, 8);
          lrow[qf][j] = lrow[qf][j] * alpha + rs;
          mrow[qf][j] = mnew;
#pragma unroll
          for (int df = 0; df < 4; ++df) yacc[qf][df][j] *= alpha;
        }
      // write P (fp16) to per-wave swizzled LDS [32 q][64 kv]; per-wave buffer,
      // within-wave ds ordering (lgkmcnt) makes this safe without a barrier
#pragma unroll
      for (int qf = 0; qf < 2; ++qf)
#pragma unroll
        for (int f = 0; f < 4; ++f)
#pragma unroll
          for (int j = 0; j < 4; ++j) {
            unsigned row = qf * 16 + gq * 4 + j;
            unsigned addr = (pw + row * 128 + (f * 16 + ln) * 2) ^ ((row & 7) << 4);
            *(ushort_t*)(lds + addr) = f2h(s[qf][f][j]);
          }
      // PV: y[32 q][64 d] += P[32 q][64 kv] * V[64 kv][64 d]
#pragma unroll
      for (int st = 0; st < 2; ++st) {
        short8 pa[2];
#pragma unroll
        for (int qf = 0; qf < 2; ++qf) {
          unsigned r = qf * 16 + ln;
          unsigned pc = (st * 64 + gq * 16) ^ ((r & 7) << 4);
          pa[qf] = *(const short8*)(lds + pw + r * 128 + pc);
        }
#pragma unroll
        for (int df = 0; df < 4; ++df) {
          unsigned row = df * 16 + ln;
          unsigned c0 = (st * 64 + gq * 16) ^ ((row & 7) << 4);
          short8 vb = *(const short8*)(lds + vb_ + row * 128 + c0);
          yacc[0][df] = mfma16(pa[0], vb, yacc[0][df]);
          yacc[1][df] = mfma16(pa[1], vb, yacc[1][df]);
        }
      }
    }
    __syncthreads();   // drain prefetch (vmcnt) + protect buffers
  }
  // epilogue: y[b][t][h*64+d] fp16
#pragma unroll
  for (int qf = 0; qf < 2; ++qf)
#pragma unroll
    for (int df = 0; df < 4; ++df)
#pragma unroll
      for (int j = 0; j < 4; ++j) {
        int t = q0 + w * 32 + qf * 16 + gq * 4 + j;
        int col = (bh & 15) * 64 + df * 16 + ln;
        size_t off = ((size_t)(bh >> 4) * 2048 + t) * 1024 + col;
        yg[off] = f2h(yacc[qf][df][j] / lrow[qf][j]);
      }
}

extern "C" void kernel_launch(void* const* d_in, const int* in_sizes, int n_in,
                              void* d_out, int out_size, void* d_ws, size_t ws_size,
                              hipStream_t stream) {
  (void)in_sizes; (void)n_in; (void)out_size; (void)ws_size;
  const float* x     = (const float*)d_in[0];
  const float* wqkv  = (const float*)d_in[1];
  const float* wproj = (const float*)d_in[2];
  float* out = (float*)d_out;
  char* ws = (char*)d_ws;
  // ws layout (bytes)
  ushort_t* xb   = (ushort_t*)(ws);               // 16MB  (reused as y after QKV GEMM)
  ushort_t* wqkt = (ushort_t*)(ws + 16777216);    // 6MB
  ushort_t* wpt  = (ushort_t*)(ws + 23068672);    // 2MB
  ushort_t* qb_  = (ushort_t*)(ws + 25165824);    // 16MB [bh][t][d]
  ushort_t* kb_  = (ushort_t*)(ws + 41943040);    // 16MB [bh][t][d]
  ushort_t* vn   = (ushort_t*)(ws + 58720256);    // 16MB [bh][t][d]
  ushort_t* vt   = (ushort_t*)(ws + 75497472);    // 16MB [bh][d][t]
  ushort_t* yb   = xb;

  cast_f32_f16<<<2048, 256, 0, stream>>>((const float4*)x, (us4*)xb, 2097152);
  tcast<<<dim3(96, 32), 256, 0, stream>>>(wqkv, wqkt, 1024, 3072);
  tcast<<<dim3(32, 32), 256, 0, stream>>>(wproj, wpt, 1024, 1024);
  gemm128<0><<<dim3(24, 64), 256, 0, stream>>>(xb, wqkt, 1024, 3072, qb_, kb_, vn, nullptr);
  transpose_v<<<dim3(32, 64), 256, 0, stream>>>(vn, vt);
  attn_kernel<<<dim3(16, 64), 256, 0, stream>>>(qb_, kb_, vt, yb);
  gemm128<1><<<dim3(8, 64), 256, 0, stream>>>(yb, wpt, 1024, 1024, nullptr, nullptr, nullptr, out);
}

// Round 5
// 228.373 us; speedup vs baseline: 1.4101x; 1.4101x over previous
//
#include <hip/hip_runtime.h>
#include <stdint.h>

typedef unsigned short ushort_t;
typedef __attribute__((ext_vector_type(8))) short short8;
typedef __attribute__((ext_vector_type(8))) _Float16 half8;
typedef __attribute__((ext_vector_type(4))) float f32x4;
typedef __attribute__((ext_vector_type(4))) unsigned short us4;

#define AS1 __attribute__((address_space(1)))
#define AS3 __attribute__((address_space(3)))

#if __has_builtin(__builtin_amdgcn_exp2f)
#define EXP2(x) __builtin_amdgcn_exp2f(x)
#else
#define EXP2(x) exp2f(x)
#endif

// scores are multiplied by 8 (the reference's /scale bug); fold into exp2 base
#define SC 11.541560327111707f  // 8 * log2(e)

__device__ __forceinline__ ushort_t f2h(float f) {
  _Float16 h = (_Float16)f;   // v_cvt_f16_f32, RNE
  return __builtin_bit_cast(unsigned short, h);
}

__device__ __forceinline__ void gload16(const void* g, void* l) {
  __builtin_amdgcn_global_load_lds((AS1 const void*)g, (AS3 void*)l, 16, 0, 0);
}

__device__ __forceinline__ f32x4 mfma16(short8 a, short8 b, f32x4 c) {
  return __builtin_amdgcn_mfma_f32_16x16x32_f16(
      __builtin_bit_cast(half8, a), __builtin_bit_cast(half8, b), c, 0, 0, 0);
}

// ---------------- cast x fp32 -> fp16 ----------------
__global__ __launch_bounds__(256) void cast_f32_f16(const float4* __restrict__ in,
                                                    us4* __restrict__ out, int n4) {
  int i = blockIdx.x * 256 + threadIdx.x;
  int stride = gridDim.x * 256;
  for (; i < n4; i += stride) {
    float4 v = in[i];
    us4 o;
    o[0] = f2h(v.x); o[1] = f2h(v.y); o[2] = f2h(v.z); o[3] = f2h(v.w);
    out[i] = o;
  }
}

// ---------------- transpose-cast W [R][C] fp32 -> Wt [C][R] fp16 ----------------
__global__ __launch_bounds__(256) void tcast(const float* __restrict__ in,
                                             ushort_t* __restrict__ out, int R, int C) {
  __shared__ __align__(16) float lt[32][33];
  const int r0 = blockIdx.y * 32, c0 = blockIdx.x * 32;
  const int i = threadIdx.x;
  const int lr = i >> 3, lc = (i & 7) * 4;
  float4 v = *(const float4*)(in + (size_t)(r0 + lr) * C + c0 + lc);
  lt[lr][lc + 0] = v.x; lt[lr][lc + 1] = v.y; lt[lr][lc + 2] = v.z; lt[lr][lc + 3] = v.w;
  __syncthreads();
  const int oc = i >> 3;          // out row (a column c of in)
  const int orr = (i & 7) * 4;    // out col (row r of in)
  us4 o;
#pragma unroll
  for (int jj = 0; jj < 4; ++jj) o[jj] = f2h(lt[orr + jj][oc]);
  *(us4*)(out + (size_t)(c0 + oc) * R + r0 + orr) = o;
}

// ---------------- 128x128 fp16 GEMM, BK=64, A[M][K] x Bt[N][K] ----------------
// MODE 0: epilogue scatters into q/k/v head layouts (fp16)
// MODE 1: epilogue writes fp32 out[M][N]
template<int MODE>
__global__ __launch_bounds__(256) void gemm128(
    const ushort_t* __restrict__ A, const ushort_t* __restrict__ Bt, int K, int N,
    ushort_t* __restrict__ qo, ushort_t* __restrict__ ko, ushort_t* __restrict__ vo,
    float* __restrict__ outp)
{
  __shared__ __align__(16) unsigned char lds[32768];   // A tile 16K, B tile 16K
  const int tid = threadIdx.x;
  const int lane = tid & 63, w = tid >> 6;
  const int ln = lane & 15, gq = lane >> 4;
  const int wr = w >> 1, wc = w & 1;
  const int m0 = blockIdx.y * 128, n0 = blockIdx.x * 128;
  const size_t ldb = (size_t)K * 2;  // row bytes
  const unsigned char* ab = (const unsigned char*)A + (size_t)m0 * ldb;
  const unsigned char* bb = (const unsigned char*)Bt + (size_t)n0 * ldb;
  f32x4 acc[4][4] = {};
  const int nkt = K >> 6;
  for (int kb = 0; kb < nkt; ++kb) {
    const unsigned char* abk = ab + kb * 128;
    const unsigned char* bbk = bb + kb * 128;
#pragma unroll
    for (int e = 0; e < 4; ++e) {
      unsigned o = e * 4096 + tid * 16;
      unsigned r = o >> 7;
      unsigned c = (o & 127) ^ ((r & 7) << 4);   // pre-swizzled source
      gload16(abk + (size_t)r * ldb + c, lds + o);
      gload16(bbk + (size_t)r * ldb + c, lds + 16384 + o);
    }
    __syncthreads();
    short8 af[4][2], bf8[4][2];
#pragma unroll
    for (int mi = 0; mi < 4; ++mi) {
      unsigned row = wr * 64 + mi * 16 + ln;
      unsigned c0 = (gq * 16) ^ ((row & 7) << 4);
      af[mi][0] = *(const short8*)(lds + row * 128 + c0);
      af[mi][1] = *(const short8*)(lds + row * 128 + (c0 ^ 64));
    }
#pragma unroll
    for (int ni = 0; ni < 4; ++ni) {
      unsigned row = wc * 64 + ni * 16 + ln;
      unsigned c0 = (gq * 16) ^ ((row & 7) << 4);
      bf8[ni][0] = *(const short8*)(lds + 16384 + row * 128 + c0);
      bf8[ni][1] = *(const short8*)(lds + 16384 + row * 128 + (c0 ^ 64));
    }
#pragma unroll
    for (int mi = 0; mi < 4; ++mi)
#pragma unroll
      for (int ni = 0; ni < 4; ++ni) {
        acc[mi][ni] = mfma16(af[mi][0], bf8[ni][0], acc[mi][ni]);
        acc[mi][ni] = mfma16(af[mi][1], bf8[ni][1], acc[mi][ni]);
      }
    __syncthreads();
  }
  // epilogue: D layout col = lane&15, row = (lane>>4)*4 + j
  if (MODE == 0) {
#pragma unroll
    for (int mi = 0; mi < 4; ++mi)
#pragma unroll
      for (int ni = 0; ni < 4; ++ni)
#pragma unroll
        for (int j = 0; j < 4; ++j) {
          int token = m0 + wr * 64 + mi * 16 + gq * 4 + j;
          int feat  = n0 + wc * 64 + ni * 16 + ln;
          int sec = feat >> 10, cc = feat & 1023;
          int hh = cc >> 6, dd = cc & 63;
          size_t off = (((size_t)(token >> 11) * 16 + hh) * 2048 + (token & 2047)) * 64 + dd;
          ushort_t valb = f2h(acc[mi][ni][j]);
          if (sec == 0) qo[off] = valb;
          else if (sec == 1) ko[off] = valb;
          else vo[off] = valb;
        }
  } else {
#pragma unroll
    for (int mi = 0; mi < 4; ++mi)
#pragma unroll
      for (int ni = 0; ni < 4; ++ni)
#pragma unroll
        for (int j = 0; j < 4; ++j) {
          int token = m0 + wr * 64 + mi * 16 + gq * 4 + j;
          int feat  = n0 + wc * 64 + ni * 16 + ln;
          outp[(size_t)token * N + feat] = acc[mi][ni][j];
        }
  }
}

// ---------------- V [bh][2048][64] -> Vt [bh][64][2048] ----------------
__global__ __launch_bounds__(256) void transpose_v(const ushort_t* __restrict__ vn,
                                                   ushort_t* __restrict__ vt) {
  __shared__ __align__(16) ushort_t lt[64][80];
  const int bh = blockIdx.y, t0 = blockIdx.x * 64;
  const int i = threadIdx.x;
  {
    const int tr = i >> 2, dc = (i & 3) * 16;
    const ushort_t* src = vn + ((size_t)bh * 2048 + t0 + tr) * 64 + dc;
    *(short8*)&lt[tr][dc] = *(const short8*)src;
    *(short8*)&lt[tr][dc + 8] = *(const short8*)(src + 8);
  }
  __syncthreads();
  {
    const int dr = i >> 2, tc = (i & 3) * 16;
    short8 a, b;
#pragma unroll
    for (int jj = 0; jj < 8; ++jj) a[jj] = (short)lt[tc + jj][dr];
#pragma unroll
    for (int jj = 0; jj < 8; ++jj) b[jj] = (short)lt[tc + 8 + jj][dr];
    ushort_t* dst = vt + ((size_t)bh * 64 + dr) * 2048 + t0 + tc;
    *(short8*)dst = a;
    *(short8*)(dst + 8) = b;
  }
}

// ---------------- flash attention: causal pair-balanced, QBLK=64, sequential phases ----------------
// Block handles q-tile `pair` then q-tile `31-pair` (constant 33 kv-tiles of work).
// Single q-state, per-phase epilogue (low VGPR). No cross-phase prefetch.
// LDS: K dbuf @0/8192, Vt dbuf @16384/24576, P per-wave @32768 + w*2048 (40960B -> 4 blocks/CU)
__global__ __launch_bounds__(256) void attn_kernel(const ushort_t* __restrict__ qg,
                                                   const ushort_t* __restrict__ kg,
                                                   const ushort_t* __restrict__ vtg,
                                                   ushort_t* __restrict__ yg) {
  __shared__ __align__(16) unsigned char lds[40960];
  const int n = blockIdx.x;                 // 0..1023
  const int xcd = n & 7, loc = n >> 3;      // XCD-grouped decode
  const int bh = xcd * 8 + (loc >> 4);      // 0..63; all 16 pair-blocks of a bh on one XCD
  const int pair = loc & 15;                // 0..15
  const int tid = threadIdx.x;
  const int lane = tid & 63, w = tid >> 6;
  const int ln = lane & 15, gq = lane >> 4;

  const unsigned char* kbase = (const unsigned char*)kg + (size_t)bh * 2048 * 128;
  const unsigned char* vbase = (const unsigned char*)vtg + (size_t)bh * 64 * 4096;
  const ushort_t* qg_bh = qg + (size_t)bh * 2048 * 64;
  const unsigned pw = 32768 + w * 2048;

  // stage kv tile t into buffer buf (K: 8KB contiguous; Vt: 64 rows x 128B, row stride 4KB)
  auto stage = [&](int buf, int t) {
    const unsigned char* kt = kbase + (size_t)t * 8192;
    const unsigned char* vt = vbase + t * 128;
#pragma unroll
    for (int e = 0; e < 2; ++e) {
      unsigned o = e * 4096 + tid * 16;
      unsigned r = o >> 7;
      unsigned c = (o & 127) ^ ((r & 7) << 4);
      gload16(kt + r * 128 + c, lds + buf * 8192 + o);
      gload16(vt + (size_t)r * 4096 + c, lds + 16384 + buf * 8192 + o);
    }
  };

  int cur = 0;
  for (int ph = 0; ph < 2; ++ph) {
    const int qt = (ph == 0) ? pair : 31 - pair;
    const int q0 = qt * 64;
    const int nt = qt + 1;

    // Q fragments (A-operand): row = lane&15, k = st*32 + gq*8 + j
    const ushort_t* qrow = qg_bh + (size_t)(q0 + w * 16 + ln) * 64;
    short8 qa0 = *(const short8*)(qrow + gq * 8);
    short8 qa1 = *(const short8*)(qrow + 32 + gq * 8);

    f32x4 yacc[4] = {};
    float mrow[4], lrow[4];
#pragma unroll
    for (int j = 0; j < 4; ++j) { mrow[j] = -3e38f; lrow[j] = 0.f; }

    stage(cur, 0);
    __syncthreads();

    for (int t = 0; t < nt; ++t) {
      if (t + 1 < nt) stage(cur ^ 1, t + 1);   // depth-1 prefetch (other buffer)
      const unsigned kb_ = cur * 8192;
      const unsigned vb_ = 16384 + cur * 8192;
      // QK^T: S[16 q][64 kv] in 4 fragments
      f32x4 s[4];
#pragma unroll
      for (int f = 0; f < 4; ++f) {
        unsigned row = f * 16 + ln;
        unsigned c0 = (gq * 16) ^ ((row & 7) << 4);
        short8 k0 = *(const short8*)(lds + kb_ + row * 128 + c0);
        short8 k1 = *(const short8*)(lds + kb_ + row * 128 + (c0 ^ 64));
        f32x4 z = {0.f, 0.f, 0.f, 0.f};
        z = mfma16(qa0, k0, z);
        s[f] = mfma16(qa1, k1, z);
      }
      if (t == nt - 1) {   // diagonal tile (kv0 == q0): mask kv > q in local coords
#pragma unroll
        for (int f = 0; f < 4; ++f) {
          int kvloc = f * 16 + ln;
#pragma unroll
          for (int j = 0; j < 4; ++j) {
            int qloc = w * 16 + gq * 4 + j;
            if (kvloc > qloc) s[f][j] = -3e38f;
          }
        }
      }
      // online softmax (row = 16 lanes of group gq; col = ln)
#pragma unroll
      for (int j = 0; j < 4; ++j) {
        float rm = fmaxf(fmaxf(s[0][j], s[1][j]), fmaxf(s[2][j], s[3][j]));
        rm = fmaxf(rm, __shfl_xor(rm, 1));
        rm = fmaxf(rm, __shfl_xor(rm, 2));
        rm = fmaxf(rm, __shfl_xor(rm, 4));
        rm = fmaxf(rm, __shfl_xor(rm, 8));
        float mnew = fmaxf(mrow[j], rm);
        float alpha = EXP2((mrow[j] - mnew) * SC);
        float rs = 0.f;
#pragma unroll
        for (int f = 0; f < 4; ++f) {
          float p = EXP2((s[f][j] - mnew) * SC);
          s[f][j] = p;
          rs += p;
        }
        rs += __shfl_xor(rs, 1);
        rs += __shfl_xor(rs, 2);
        rs += __shfl_xor(rs, 4);
        rs += __shfl_xor(rs, 8);
        lrow[j] = lrow[j] * alpha + rs;
        mrow[j] = mnew;
#pragma unroll
        for (int df = 0; df < 4; ++df) yacc[df][j] *= alpha;
      }
      // write P (fp16) into per-wave swizzled LDS [16 q][64 kv]; per-wave buffer,
      // within-wave ds ordering (lgkmcnt) makes this safe without a barrier
#pragma unroll
      for (int f = 0; f < 4; ++f)
#pragma unroll
        for (int j = 0; j < 4; ++j) {
          unsigned row = gq * 4 + j;
          unsigned addr = (pw + row * 128 + (f * 16 + ln) * 2) ^ ((row & 7) << 4);
          *(ushort_t*)(lds + addr) = f2h(s[f][j]);
        }
      // PV: y[16 q][64 d] += P[16 q][64 kv] * V[64 kv][64 d]
#pragma unroll
      for (int st = 0; st < 2; ++st) {
        unsigned pc = (st * 64 + gq * 16) ^ ((ln & 7) << 4);
        short8 pa = *(const short8*)(lds + pw + ln * 128 + pc);
#pragma unroll
        for (int df = 0; df < 4; ++df) {
          unsigned row = df * 16 + ln;
          unsigned c0 = (st * 64 + gq * 16) ^ ((row & 7) << 4);
          short8 vb = *(const short8*)(lds + vb_ + row * 128 + c0);
          yacc[df] = mfma16(pa, vb, yacc[df]);
        }
      }
      __syncthreads();   // drain prefetch + protect buffers
      cur ^= 1;
    }

    // epilogue for this phase: y[b][t][h*64+d] fp16
#pragma unroll
    for (int df = 0; df < 4; ++df)
#pragma unroll
      for (int j = 0; j < 4; ++j) {
        int tq = q0 + w * 16 + gq * 4 + j;
        int col = (bh & 15) * 64 + df * 16 + ln;
        size_t off = ((size_t)(bh >> 4) * 2048 + tq) * 1024 + col;
        yg[off] = f2h(yacc[df][j] / lrow[j]);
      }
  }
}

extern "C" void kernel_launch(void* const* d_in, const int* in_sizes, int n_in,
                              void* d_out, int out_size, void* d_ws, size_t ws_size,
                              hipStream_t stream) {
  (void)in_sizes; (void)n_in; (void)out_size; (void)ws_size;
  const float* x     = (const float*)d_in[0];
  const float* wqkv  = (const float*)d_in[1];
  const float* wproj = (const float*)d_in[2];
  float* out = (float*)d_out;
  char* ws = (char*)d_ws;
  // ws layout (bytes)
  ushort_t* xb   = (ushort_t*)(ws);               // 16MB  (reused as y after QKV GEMM)
  ushort_t* wqkt = (ushort_t*)(ws + 16777216);    // 6MB
  ushort_t* wpt  = (ushort_t*)(ws + 23068672);    // 2MB
  ushort_t* qb_  = (ushort_t*)(ws + 25165824);    // 16MB [bh][t][d]
  ushort_t* kb_  = (ushort_t*)(ws + 41943040);    // 16MB [bh][t][d]
  ushort_t* vn   = (ushort_t*)(ws + 58720256);    // 16MB [bh][t][d]
  ushort_t* vt   = (ushort_t*)(ws + 75497472);    // 16MB [bh][d][t]
  ushort_t* yb   = xb;

  cast_f32_f16<<<2048, 256, 0, stream>>>((const float4*)x, (us4*)xb, 2097152);
  tcast<<<dim3(96, 32), 256, 0, stream>>>(wqkv, wqkt, 1024, 3072);
  tcast<<<dim3(32, 32), 256, 0, stream>>>(wproj, wpt, 1024, 1024);
  gemm128<0><<<dim3(24, 64), 256, 0, stream>>>(xb, wqkt, 1024, 3072, qb_, kb_, vn, nullptr);
  transpose_v<<<dim3(32, 64), 256, 0, stream>>>(vn, vt);
  attn_kernel<<<1024, 256, 0, stream>>>(qb_, kb_, vt, yb);
  gemm128<1><<<dim3(8, 64), 256, 0, stream>>>(yb, wpt, 1024, 1024, nullptr, nullptr, nullptr, out);
}

// Round 9
// 196.969 us; speedup vs baseline: 1.6350x; 1.1594x over previous
//
#include <hip/hip_runtime.h>
#include <stdint.h>

typedef unsigned short ushort_t;
typedef __attribute__((ext_vector_type(8))) short short8;
typedef __attribute__((ext_vector_type(8))) _Float16 half8;
typedef __attribute__((ext_vector_type(4))) float f32x4;
typedef __attribute__((ext_vector_type(4))) unsigned short us4;

#define AS1 __attribute__((address_space(1)))
#define AS3 __attribute__((address_space(3)))

#if __has_builtin(__builtin_amdgcn_exp2f)
#define EXP2(x) __builtin_amdgcn_exp2f(x)
#else
#define EXP2(x) exp2f(x)
#endif

// scores are multiplied by 8 (the reference's /scale bug); fold into exp2 base
#define SC 11.541560327111707f  // 8 * log2(e)

__device__ __forceinline__ ushort_t f2h(float f) {
  _Float16 h = (_Float16)f;   // v_cvt_f16_f32, RNE
  return __builtin_bit_cast(unsigned short, h);
}

__device__ __forceinline__ void gload16(const void* g, void* l) {
  __builtin_amdgcn_global_load_lds((AS1 const void*)g, (AS3 void*)l, 16, 0, 0);
}

__device__ __forceinline__ f32x4 mfma16(short8 a, short8 b, f32x4 c) {
  return __builtin_amdgcn_mfma_f32_16x16x32_f16(
      __builtin_bit_cast(half8, a), __builtin_bit_cast(half8, b), c, 0, 0, 0);
}

// ---------------- cast x fp32 -> fp16 ----------------
__global__ __launch_bounds__(256) void cast_f32_f16(const float4* __restrict__ in,
                                                    us4* __restrict__ out, int n4) {
  int i = blockIdx.x * 256 + threadIdx.x;
  int stride = gridDim.x * 256;
  for (; i < n4; i += stride) {
    float4 v = in[i];
    us4 o;
    o[0] = f2h(v.x); o[1] = f2h(v.y); o[2] = f2h(v.z); o[3] = f2h(v.w);
    out[i] = o;
  }
}

// ---------------- transpose-cast W [R][C] fp32 -> Wt [C][R] fp16 ----------------
__global__ __launch_bounds__(256) void tcast(const float* __restrict__ in,
                                             ushort_t* __restrict__ out, int R, int C) {
  __shared__ __align__(16) float lt[32][33];
  const int r0 = blockIdx.y * 32, c0 = blockIdx.x * 32;
  const int i = threadIdx.x;
  const int lr = i >> 3, lc = (i & 7) * 4;
  float4 v = *(const float4*)(in + (size_t)(r0 + lr) * C + c0 + lc);
  lt[lr][lc + 0] = v.x; lt[lr][lc + 1] = v.y; lt[lr][lc + 2] = v.z; lt[lr][lc + 3] = v.w;
  __syncthreads();
  const int oc = i >> 3;          // out row (a column c of in)
  const int orr = (i & 7) * 4;    // out col (row r of in)
  us4 o;
#pragma unroll
  for (int jj = 0; jj < 4; ++jj) o[jj] = f2h(lt[orr + jj][oc]);
  *(us4*)(out + (size_t)(c0 + oc) * R + r0 + orr) = o;
}

// ---------------- 128x128 fp16 GEMM, BK=64, A[M][K] x Bt[N][K] ----------------
// MODE 0: epilogue scatters into q/k/v head layouts (fp16)
// MODE 1: epilogue writes fp32 out[M][N]
template<int MODE>
__global__ __launch_bounds__(256) void gemm128(
    const ushort_t* __restrict__ A, const ushort_t* __restrict__ Bt, int K, int N,
    ushort_t* __restrict__ qo, ushort_t* __restrict__ ko, ushort_t* __restrict__ vo,
    float* __restrict__ outp)
{
  __shared__ __align__(16) unsigned char lds[32768];   // A tile 16K, B tile 16K
  const int tid = threadIdx.x;
  const int lane = tid & 63, w = tid >> 6;
  const int ln = lane & 15, gq = lane >> 4;
  const int wr = w >> 1, wc = w & 1;
  const int m0 = blockIdx.y * 128, n0 = blockIdx.x * 128;
  const size_t ldb = (size_t)K * 2;  // row bytes
  const unsigned char* ab = (const unsigned char*)A + (size_t)m0 * ldb;
  const unsigned char* bb = (const unsigned char*)Bt + (size_t)n0 * ldb;
  f32x4 acc[4][4] = {};
  const int nkt = K >> 6;
  for (int kb = 0; kb < nkt; ++kb) {
    const unsigned char* abk = ab + kb * 128;
    const unsigned char* bbk = bb + kb * 128;
#pragma unroll
    for (int e = 0; e < 4; ++e) {
      unsigned o = e * 4096 + tid * 16;
      unsigned r = o >> 7;
      unsigned c = (o & 127) ^ ((r & 7) << 4);   // pre-swizzled source
      gload16(abk + (size_t)r * ldb + c, lds + o);
      gload16(bbk + (size_t)r * ldb + c, lds + 16384 + o);
    }
    __syncthreads();
    short8 af[4][2], bf8[4][2];
#pragma unroll
    for (int mi = 0; mi < 4; ++mi) {
      unsigned row = wr * 64 + mi * 16 + ln;
      unsigned c0 = (gq * 16) ^ ((row & 7) << 4);
      af[mi][0] = *(const short8*)(lds + row * 128 + c0);
      af[mi][1] = *(const short8*)(lds + row * 128 + (c0 ^ 64));
    }
#pragma unroll
    for (int ni = 0; ni < 4; ++ni) {
      unsigned row = wc * 64 + ni * 16 + ln;
      unsigned c0 = (gq * 16) ^ ((row & 7) << 4);
      bf8[ni][0] = *(const short8*)(lds + 16384 + row * 128 + c0);
      bf8[ni][1] = *(const short8*)(lds + 16384 + row * 128 + (c0 ^ 64));
    }
#pragma unroll
    for (int mi = 0; mi < 4; ++mi)
#pragma unroll
      for (int ni = 0; ni < 4; ++ni) {
        acc[mi][ni] = mfma16(af[mi][0], bf8[ni][0], acc[mi][ni]);
        acc[mi][ni] = mfma16(af[mi][1], bf8[ni][1], acc[mi][ni]);
      }
    __syncthreads();
  }
  // epilogue: D layout col = lane&15, row = (lane>>4)*4 + j
  if (MODE == 0) {
#pragma unroll
    for (int mi = 0; mi < 4; ++mi)
#pragma unroll
      for (int ni = 0; ni < 4; ++ni)
#pragma unroll
        for (int j = 0; j < 4; ++j) {
          int token = m0 + wr * 64 + mi * 16 + gq * 4 + j;
          int feat  = n0 + wc * 64 + ni * 16 + ln;
          int sec = feat >> 10, cc = feat & 1023;
          int hh = cc >> 6, dd = cc & 63;
          size_t off = (((size_t)(token >> 11) * 16 + hh) * 2048 + (token & 2047)) * 64 + dd;
          ushort_t valb = f2h(acc[mi][ni][j]);
          if (sec == 0) qo[off] = valb;
          else if (sec == 1) ko[off] = valb;
          else vo[off] = valb;
        }
  } else {
#pragma unroll
    for (int mi = 0; mi < 4; ++mi)
#pragma unroll
      for (int ni = 0; ni < 4; ++ni)
#pragma unroll
        for (int j = 0; j < 4; ++j) {
          int token = m0 + wr * 64 + mi * 16 + gq * 4 + j;
          int feat  = n0 + wc * 64 + ni * 16 + ln;
          outp[(size_t)token * N + feat] = acc[mi][ni][j];
        }
  }
}

// ---------------- V [bh][2048][64] -> Vt [bh][64][2048] ----------------
__global__ __launch_bounds__(256) void transpose_v(const ushort_t* __restrict__ vn,
                                                   ushort_t* __restrict__ vt) {
  __shared__ __align__(16) ushort_t lt[64][80];
  const int bh = blockIdx.y, t0 = blockIdx.x * 64;
  const int i = threadIdx.x;
  {
    const int tr = i >> 2, dc = (i & 3) * 16;
    const ushort_t* src = vn + ((size_t)bh * 2048 + t0 + tr) * 64 + dc;
    *(short8*)&lt[tr][dc] = *(const short8*)src;
    *(short8*)&lt[tr][dc + 8] = *(const short8*)(src + 8);
  }
  __syncthreads();
  {
    const int dr = i >> 2, tc = (i & 3) * 16;
    short8 a, b;
#pragma unroll
    for (int jj = 0; jj < 8; ++jj) a[jj] = (short)lt[tc + jj][dr];
#pragma unroll
    for (int jj = 0; jj < 8; ++jj) b[jj] = (short)lt[tc + 8 + jj][dr];
    ushort_t* dst = vt + ((size_t)bh * 64 + dr) * 2048 + t0 + tc;
    *(short8*)dst = a;
    *(short8*)(dst + 8) = b;
  }
}

// ---------------- flash attention: causal pair-balanced, QBLK=64, sequential phases ----------------
// Swapped QK^T (mfma(K,Q) -> S^T, col=q=ln): softmax is lane-local per q-row,
// reduce = 15 in-lane ops + 2 shfl. P-write packs 4 halves per ds_write_b64.
// LDS: K dbuf @0/8192, Vt dbuf @16384/24576, P per-wave @32768 + w*2048 (40960B -> 4 blocks/CU)
__global__ __launch_bounds__(256) void attn_kernel(const ushort_t* __restrict__ qg,
                                                   const ushort_t* __restrict__ kg,
                                                   const ushort_t* __restrict__ vtg,
                                                   ushort_t* __restrict__ yg) {
  __shared__ __align__(16) unsigned char lds[40960];
  const int n = blockIdx.x;                 // 0..1023
  const int xcd = n & 7, loc = n >> 3;      // XCD-grouped decode
  const int bh = xcd * 8 + (loc >> 4);      // 0..63; all 16 pair-blocks of a bh on one XCD
  const int pair = loc & 15;                // 0..15
  const int tid = threadIdx.x;
  const int lane = tid & 63, w = tid >> 6;
  const int ln = lane & 15, gq = lane >> 4;

  const unsigned char* kbase = (const unsigned char*)kg + (size_t)bh * 2048 * 128;
  const unsigned char* vbase = (const unsigned char*)vtg + (size_t)bh * 64 * 4096;
  const ushort_t* qg_bh = qg + (size_t)bh * 2048 * 64;
  const unsigned pw = 32768 + w * 2048;

  // stage kv tile t into buffer buf (K: 8KB contiguous; Vt: 64 rows x 128B, row stride 4KB)
  auto stage = [&](int buf, int t) {
    const unsigned char* kt = kbase + (size_t)t * 8192;
    const unsigned char* vt = vbase + t * 128;
#pragma unroll
    for (int e = 0; e < 2; ++e) {
      unsigned o = e * 4096 + tid * 16;
      unsigned r = o >> 7;
      unsigned c = (o & 127) ^ ((r & 7) << 4);
      gload16(kt + r * 128 + c, lds + buf * 8192 + o);
      gload16(vt + (size_t)r * 4096 + c, lds + 16384 + buf * 8192 + o);
    }
  };

  int cur = 0;
  for (int ph = 0; ph < 2; ++ph) {
    const int qt = (ph == 0) ? pair : 31 - pair;
    const int q0 = qt * 64;
    const int nt = qt + 1;

    // Q fragments: lane ln holds q-row (w*16+ln), k = st*32 + gq*8 + j
    // (identical layout serves as B-operand for the swapped QK^T)
    const ushort_t* qrow = qg_bh + (size_t)(q0 + w * 16 + ln) * 64;
    short8 qa0 = *(const short8*)(qrow + gq * 8);
    short8 qa1 = *(const short8*)(qrow + 32 + gq * 8);

    f32x4 yacc[4] = {};
    float mrow = -3e38f, lrow = 0.f;   // lane-local state for q-row = w*16+ln

    stage(cur, 0);
    __syncthreads();

    for (int t = 0; t < nt; ++t) {
      if (t + 1 < nt) stage(cur ^ 1, t + 1);   // depth-1 prefetch (other buffer)
      const unsigned kb_ = cur * 8192;
      const unsigned vb_ = 16384 + cur * 8192;
      // swapped QK^T: S^T[kv][q] fragments; col=ln=q, row=gq*4+j (+f*16 = kv)
      f32x4 s[4];
#pragma unroll
      for (int f = 0; f < 4; ++f) {
        unsigned row = f * 16 + ln;
        unsigned c0 = (gq * 16) ^ ((row & 7) << 4);
        short8 k0 = *(const short8*)(lds + kb_ + row * 128 + c0);
        short8 k1 = *(const short8*)(lds + kb_ + row * 128 + (c0 ^ 64));
        f32x4 z = {0.f, 0.f, 0.f, 0.f};
        z = mfma16(k0, qa0, z);
        s[f] = mfma16(k1, qa1, z);
      }
      if (t == nt - 1) {   // diagonal tile (kv0 == q0): mask kv > q in local coords
        int qloc = w * 16 + ln;
#pragma unroll
        for (int f = 0; f < 4; ++f) {
          int kvb = f * 16 + gq * 4;
#pragma unroll
          for (int j = 0; j < 4; ++j)
            if (kvb + j > qloc) s[f][j] = -3e38f;
        }
      }
      // online softmax: lane holds 16 scores all for q = w*16+ln
      {
        float rm = s[0][0];
#pragma unroll
        for (int f = 0; f < 4; ++f)
#pragma unroll
          for (int j = 0; j < 4; ++j) rm = fmaxf(rm, s[f][j]);
        rm = fmaxf(rm, __shfl_xor(rm, 16));
        rm = fmaxf(rm, __shfl_xor(rm, 32));
        float mnew = fmaxf(mrow, rm);
        float alpha = EXP2((mrow - mnew) * SC);
        float rs = 0.f;
#pragma unroll
        for (int f = 0; f < 4; ++f)
#pragma unroll
          for (int j = 0; j < 4; ++j) {
            float p = EXP2((s[f][j] - mnew) * SC);
            s[f][j] = p;
            rs += p;
          }
        rs += __shfl_xor(rs, 16);
        rs += __shfl_xor(rs, 32);
        lrow = lrow * alpha + rs;
        mrow = mnew;
        // broadcast alpha to yacc rows (yacc row q = gq*4+j; alpha lives at lane q)
#pragma unroll
        for (int j = 0; j < 4; ++j) {
          float aj = __shfl(alpha, gq * 4 + j);
#pragma unroll
          for (int df = 0; df < 4; ++df) yacc[df][j] *= aj;
        }
      }
      // write P^T -> LDS as P[16 q][64 kv]: lane owns row q=ln, cols kv=f*16+gq*4..+3
      // 4 contiguous halves -> one 8B write; swizzle flips only bit4 (16B) so 8B-aligned ok
#pragma unroll
      for (int f = 0; f < 4; ++f) {
        us4 pk;
#pragma unroll
        for (int j = 0; j < 4; ++j) pk[j] = f2h(s[f][j]);
        unsigned addr = (pw + ln * 128 + (f * 16 + gq * 4) * 2) ^ ((ln & 7) << 4);
        *(us4*)(lds + addr) = pk;
      }
      // PV: y[16 q][64 d] += P[16 q][64 kv] * V[64 kv][64 d]  (unchanged)
#pragma unroll
      for (int st = 0; st < 2; ++st) {
        unsigned pc = (st * 64 + gq * 16) ^ ((ln & 7) << 4);
        short8 pa = *(const short8*)(lds + pw + ln * 128 + pc);
#pragma unroll
        for (int df = 0; df < 4; ++df) {
          unsigned row = df * 16 + ln;
          unsigned c0 = (st * 64 + gq * 16) ^ ((row & 7) << 4);
          short8 vb = *(const short8*)(lds + vb_ + row * 128 + c0);
          yacc[df] = mfma16(pa, vb, yacc[df]);
        }
      }
      __syncthreads();   // drain prefetch + protect buffers
      cur ^= 1;
    }

    // epilogue for this phase: y[b][t][h*64+d] fp16 (lrow lives at lane q; broadcast)
#pragma unroll
    for (int j = 0; j < 4; ++j) {
      float lj = __shfl(lrow, gq * 4 + j);
      float rl = 1.0f / lj;
      int tq = q0 + w * 16 + gq * 4 + j;
#pragma unroll
      for (int df = 0; df < 4; ++df) {
        int col = (bh & 15) * 64 + df * 16 + ln;
        size_t off = ((size_t)(bh >> 4) * 2048 + tq) * 1024 + col;
        yg[off] = f2h(yacc[df][j] * rl);
      }
    }
  }
}

extern "C" void kernel_launch(void* const* d_in, const int* in_sizes, int n_in,
                              void* d_out, int out_size, void* d_ws, size_t ws_size,
                              hipStream_t stream) {
  (void)in_sizes; (void)n_in; (void)out_size; (void)ws_size;
  const float* x     = (const float*)d_in[0];
  const float* wqkv  = (const float*)d_in[1];
  const float* wproj = (const float*)d_in[2];
  float* out = (float*)d_out;
  char* ws = (char*)d_ws;
  // ws layout (bytes)
  ushort_t* xb   = (ushort_t*)(ws);               // 16MB  (reused as y after QKV GEMM)
  ushort_t* wqkt = (ushort_t*)(ws + 16777216);    // 6MB
  ushort_t* wpt  = (ushort_t*)(ws + 23068672);    // 2MB
  ushort_t* qb_  = (ushort_t*)(ws + 25165824);    // 16MB [bh][t][d]
  ushort_t* kb_  = (ushort_t*)(ws + 41943040);    // 16MB [bh][t][d]
  ushort_t* vn   = (ushort_t*)(ws + 58720256);    // 16MB [bh][t][d]
  ushort_t* vt   = (ushort_t*)(ws + 75497472);    // 16MB [bh][d][t]
  ushort_t* yb   = xb;

  cast_f32_f16<<<2048, 256, 0, stream>>>((const float4*)x, (us4*)xb, 2097152);
  tcast<<<dim3(96, 32), 256, 0, stream>>>(wqkv, wqkt, 1024, 3072);
  tcast<<<dim3(32, 32), 256, 0, stream>>>(wproj, wpt, 1024, 1024);
  gemm128<0><<<dim3(24, 64), 256, 0, stream>>>(xb, wqkt, 1024, 3072, qb_, kb_, vn, nullptr);
  transpose_v<<<dim3(32, 64), 256, 0, stream>>>(vn, vt);
  attn_kernel<<<1024, 256, 0, stream>>>(qb_, kb_, vt, yb);
  gemm128<1><<<dim3(8, 64), 256, 0, stream>>>(yb, wpt, 1024, 1024, nullptr, nullptr, nullptr, out);
}

// Round 10
// 191.377 us; speedup vs baseline: 1.6827x; 1.0292x over previous
//
#include <hip/hip_runtime.h>
#include <stdint.h>

typedef unsigned short ushort_t;
typedef __attribute__((ext_vector_type(8))) short short8;
typedef __attribute__((ext_vector_type(8))) _Float16 half8;
typedef __attribute__((ext_vector_type(4))) float f32x4;
typedef __attribute__((ext_vector_type(4))) unsigned short us4;

#define AS1 __attribute__((address_space(1)))
#define AS3 __attribute__((address_space(3)))

#if __has_builtin(__builtin_amdgcn_exp2f)
#define EXP2(x) __builtin_amdgcn_exp2f(x)
#else
#define EXP2(x) exp2f(x)
#endif

// scores are multiplied by 8 (the reference's /scale bug); fold into exp2 base
#define SC 11.541560327111707f  // 8 * log2(e)

__device__ __forceinline__ ushort_t f2h(float f) {
  _Float16 h = (_Float16)f;   // v_cvt_f16_f32, RNE
  return __builtin_bit_cast(unsigned short, h);
}

__device__ __forceinline__ void gload16(const void* g, void* l) {
  __builtin_amdgcn_global_load_lds((AS1 const void*)g, (AS3 void*)l, 16, 0, 0);
}

__device__ __forceinline__ f32x4 mfma16(short8 a, short8 b, f32x4 c) {
  return __builtin_amdgcn_mfma_f32_16x16x32_f16(
      __builtin_bit_cast(half8, a), __builtin_bit_cast(half8, b), c, 0, 0, 0);
}

// ---------------- cast x fp32 -> fp16 ----------------
__global__ __launch_bounds__(256) void cast_f32_f16(const float4* __restrict__ in,
                                                    us4* __restrict__ out, int n4) {
  int i = blockIdx.x * 256 + threadIdx.x;
  int stride = gridDim.x * 256;
  for (; i < n4; i += stride) {
    float4 v = in[i];
    us4 o;
    o[0] = f2h(v.x); o[1] = f2h(v.y); o[2] = f2h(v.z); o[3] = f2h(v.w);
    out[i] = o;
  }
}

// ---------------- transpose-cast W [R][C] fp32 -> Wt [C][R] fp16 ----------------
__global__ __launch_bounds__(256) void tcast(const float* __restrict__ in,
                                             ushort_t* __restrict__ out, int R, int C) {
  __shared__ __align__(16) float lt[32][33];
  const int r0 = blockIdx.y * 32, c0 = blockIdx.x * 32;
  const int i = threadIdx.x;
  const int lr = i >> 3, lc = (i & 7) * 4;
  float4 v = *(const float4*)(in + (size_t)(r0 + lr) * C + c0 + lc);
  lt[lr][lc + 0] = v.x; lt[lr][lc + 1] = v.y; lt[lr][lc + 2] = v.z; lt[lr][lc + 3] = v.w;
  __syncthreads();
  const int oc = i >> 3;          // out row (a column c of in)
  const int orr = (i & 7) * 4;    // out col (row r of in)
  us4 o;
#pragma unroll
  for (int jj = 0; jj < 4; ++jj) o[jj] = f2h(lt[orr + jj][oc]);
  *(us4*)(out + (size_t)(c0 + oc) * R + r0 + orr) = o;
}

// ---------------- 128x128 fp16 GEMM, BK=64, A[M][K] x Bt[N][K] ----------------
// MODE 0: epilogue scatters into q/k/v head layouts (fp16)
// MODE 1: epilogue writes fp32 out[M][N]
template<int MODE>
__global__ __launch_bounds__(256) void gemm128(
    const ushort_t* __restrict__ A, const ushort_t* __restrict__ Bt, int K, int N,
    ushort_t* __restrict__ qo, ushort_t* __restrict__ ko, ushort_t* __restrict__ vo,
    float* __restrict__ outp)
{
  __shared__ __align__(16) unsigned char lds[32768];   // A tile 16K, B tile 16K
  const int tid = threadIdx.x;
  const int lane = tid & 63, w = tid >> 6;
  const int ln = lane & 15, gq = lane >> 4;
  const int wr = w >> 1, wc = w & 1;
  const int m0 = blockIdx.y * 128, n0 = blockIdx.x * 128;
  const size_t ldb = (size_t)K * 2;  // row bytes
  const unsigned char* ab = (const unsigned char*)A + (size_t)m0 * ldb;
  const unsigned char* bb = (const unsigned char*)Bt + (size_t)n0 * ldb;
  f32x4 acc[4][4] = {};
  const int nkt = K >> 6;
  for (int kb = 0; kb < nkt; ++kb) {
    const unsigned char* abk = ab + kb * 128;
    const unsigned char* bbk = bb + kb * 128;
#pragma unroll
    for (int e = 0; e < 4; ++e) {
      unsigned o = e * 4096 + tid * 16;
      unsigned r = o >> 7;
      unsigned c = (o & 127) ^ ((r & 7) << 4);   // pre-swizzled source
      gload16(abk + (size_t)r * ldb + c, lds + o);
      gload16(bbk + (size_t)r * ldb + c, lds + 16384 + o);
    }
    __syncthreads();
    short8 af[4][2], bf8[4][2];
#pragma unroll
    for (int mi = 0; mi < 4; ++mi) {
      unsigned row = wr * 64 + mi * 16 + ln;
      unsigned c0 = (gq * 16) ^ ((row & 7) << 4);
      af[mi][0] = *(const short8*)(lds + row * 128 + c0);
      af[mi][1] = *(const short8*)(lds + row * 128 + (c0 ^ 64));
    }
#pragma unroll
    for (int ni = 0; ni < 4; ++ni) {
      unsigned row = wc * 64 + ni * 16 + ln;
      unsigned c0 = (gq * 16) ^ ((row & 7) << 4);
      bf8[ni][0] = *(const short8*)(lds + 16384 + row * 128 + c0);
      bf8[ni][1] = *(const short8*)(lds + 16384 + row * 128 + (c0 ^ 64));
    }
#pragma unroll
    for (int mi = 0; mi < 4; ++mi)
#pragma unroll
      for (int ni = 0; ni < 4; ++ni) {
        acc[mi][ni] = mfma16(af[mi][0], bf8[ni][0], acc[mi][ni]);
        acc[mi][ni] = mfma16(af[mi][1], bf8[ni][1], acc[mi][ni]);
      }
    __syncthreads();
  }
  // epilogue: D layout col = lane&15, row = (lane>>4)*4 + j
  if (MODE == 0) {
#pragma unroll
    for (int mi = 0; mi < 4; ++mi)
#pragma unroll
      for (int ni = 0; ni < 4; ++ni)
#pragma unroll
        for (int j = 0; j < 4; ++j) {
          int token = m0 + wr * 64 + mi * 16 + gq * 4 + j;
          int feat  = n0 + wc * 64 + ni * 16 + ln;
          int sec = feat >> 10, cc = feat & 1023;
          int hh = cc >> 6, dd = cc & 63;
          size_t off = (((size_t)(token >> 11) * 16 + hh) * 2048 + (token & 2047)) * 64 + dd;
          ushort_t valb = f2h(acc[mi][ni][j]);
          if (sec == 0) qo[off] = valb;
          else if (sec == 1) ko[off] = valb;
          else vo[off] = valb;
        }
  } else {
#pragma unroll
    for (int mi = 0; mi < 4; ++mi)
#pragma unroll
      for (int ni = 0; ni < 4; ++ni)
#pragma unroll
        for (int j = 0; j < 4; ++j) {
          int token = m0 + wr * 64 + mi * 16 + gq * 4 + j;
          int feat  = n0 + wc * 64 + ni * 16 + ln;
          outp[(size_t)token * N + feat] = acc[mi][ni][j];
        }
  }
}

// ---------------- V [bh][2048][64] -> Vt [bh][64][2048] ----------------
__global__ __launch_bounds__(256) void transpose_v(const ushort_t* __restrict__ vn,
                                                   ushort_t* __restrict__ vt) {
  __shared__ __align__(16) ushort_t lt[64][80];
  const int bh = blockIdx.y, t0 = blockIdx.x * 64;
  const int i = threadIdx.x;
  {
    const int tr = i >> 2, dc = (i & 3) * 16;
    const ushort_t* src = vn + ((size_t)bh * 2048 + t0 + tr) * 64 + dc;
    *(short8*)&lt[tr][dc] = *(const short8*)src;
    *(short8*)&lt[tr][dc + 8] = *(const short8*)(src + 8);
  }
  __syncthreads();
  {
    const int dr = i >> 2, tc = (i & 3) * 16;
    short8 a, b;
#pragma unroll
    for (int jj = 0; jj < 8; ++jj) a[jj] = (short)lt[tc + jj][dr];
#pragma unroll
    for (int jj = 0; jj < 8; ++jj) b[jj] = (short)lt[tc + 8 + jj][dr];
    ushort_t* dst = vt + ((size_t)bh * 64 + dr) * 2048 + t0 + tc;
    *(short8*)dst = a;
    *(short8*)(dst + 8) = b;
  }
}

// ---------------- flash attention: causal pair-balanced, QBLK=64, KVBLK=128 ----------------
// Swapped QK^T (softmax lane-local, q = lane&15) + deferred rescale (THR=8 in exp2 units).
// One staged 128-kv tile per iteration: 1 barrier / 128 kv, one softmax finish per 128 kv.
// LDS: K dbuf @0/16384 (128x128B), Vt dbuf @32768/49152 (64x256B),
//      P per-wave @65536 + w*4096 (16q x 256B). Total 81920B -> 2 blocks/CU.
__global__ __launch_bounds__(256) void attn_kernel(const ushort_t* __restrict__ qg,
                                                   const ushort_t* __restrict__ kg,
                                                   const ushort_t* __restrict__ vtg,
                                                   ushort_t* __restrict__ yg) {
  __shared__ __align__(16) unsigned char lds[81920];
  const int n = blockIdx.x;                 // 0..1023
  const int xcd = n & 7, loc = n >> 3;      // XCD-grouped decode
  const int bh = xcd * 8 + (loc >> 4);      // 0..63; all 16 pair-blocks of a bh on one XCD
  const int pair = loc & 15;                // 0..15
  const int tid = threadIdx.x;
  const int lane = tid & 63, w = tid >> 6;
  const int ln = lane & 15, gq = lane >> 4;

  const unsigned char* kbase = (const unsigned char*)kg + (size_t)bh * 2048 * 128;
  const unsigned char* vbase = (const unsigned char*)vtg + (size_t)bh * 64 * 4096;
  const ushort_t* qg_bh = qg + (size_t)bh * 2048 * 64;
  const unsigned pw = 65536 + w * 4096;

  // stage 128-kv tile t2 into buffer buf.
  // K: 16KB contiguous rows [t2*128, +128) x 128B. Vt: 64 rows x 256B (row stride 4096B).
  auto stage = [&](int buf, int t2) {
    const unsigned char* kt = kbase + (size_t)t2 * 16384;
    const unsigned char* vt = vbase + t2 * 256;
#pragma unroll
    for (int e = 0; e < 4; ++e) {
      unsigned o = e * 4096 + tid * 16;
      {  // K: row r (0..127), 128B rows
        unsigned r = o >> 7;
        unsigned c = (o & 127) ^ ((r & 7) << 4);
        gload16(kt + r * 128 + c, lds + buf * 16384 + o);
      }
      {  // Vt: row r (0..63), 256B cols within 4096B-stride rows
        unsigned r = o >> 8;
        unsigned c = (o & 255) ^ ((r & 7) << 4);
        gload16(vt + (size_t)r * 4096 + c, lds + 32768 + buf * 16384 + o);
      }
    }
  };

  int cur = 0;
  for (int ph = 0; ph < 2; ++ph) {
    const int qt = (ph == 0) ? pair : 31 - pair;
    const int q0 = qt * 64;
    const int nt2 = (qt + 2) >> 1;          // ceil((qt+1)/2) 128-kv tiles

    // Q fragments: lane ln holds q-row (w*16+ln), k = st*32 + gq*8 + j
    const ushort_t* qrow = qg_bh + (size_t)(q0 + w * 16 + ln) * 64;
    short8 qa0 = *(const short8*)(qrow + gq * 8);
    short8 qa1 = *(const short8*)(qrow + 32 + gq * 8);

    f32x4 yacc[4] = {};
    float mrow = -3e38f, lrow = 0.f;   // lane-local state for q-row = w*16+ln
    const int qglob = q0 + w * 16 + ln;

    stage(cur, 0);
    __syncthreads();

    for (int t2 = 0; t2 < nt2; ++t2) {
      if (t2 + 1 < nt2) stage(cur ^ 1, t2 + 1);   // depth-1 prefetch (other buffer)
      const unsigned kb_ = cur * 16384;
      const unsigned vb_ = 32768 + cur * 16384;
      // swapped QK^T over 128 kv: S^T fragments; lane (gq,ln): q=ln, kv=f*16+gq*4+j
      f32x4 s[8];
#pragma unroll
      for (int f = 0; f < 8; ++f) {
        unsigned row = f * 16 + ln;
        unsigned c0 = (gq * 16) ^ ((row & 7) << 4);
        short8 k0 = *(const short8*)(lds + kb_ + row * 128 + c0);
        short8 k1 = *(const short8*)(lds + kb_ + row * 128 + (c0 ^ 64));
        f32x4 z = {0.f, 0.f, 0.f, 0.f};
        z = mfma16(k0, qa0, z);
        s[f] = mfma16(k1, qa1, z);
      }
      if (t2 == nt2 - 1) {   // diagonal 128-tile: mask kv > q (global coords)
        const int kv0 = t2 * 128;
#pragma unroll
        for (int f = 0; f < 8; ++f) {
          int kvb = kv0 + f * 16 + gq * 4;
#pragma unroll
          for (int j = 0; j < 4; ++j)
            if (kvb + j > qglob) s[f][j] = -3e38f;
        }
      }
      // online softmax (one finish per 128 kv), deferred rescale (THR=8 exp2-units)
      {
        float rm = s[0][0];
#pragma unroll
        for (int f = 0; f < 8; ++f)
#pragma unroll
          for (int j = 0; j < 4; ++j) rm = fmaxf(rm, s[f][j]);
        rm = fmaxf(rm, __shfl_xor(rm, 16));
        rm = fmaxf(rm, __shfl_xor(rm, 32));
        if (__any((rm - mrow) * SC > 8.0f)) {
          float mnew = fmaxf(mrow, rm);
          float alpha = EXP2((mrow - mnew) * SC);
          lrow *= alpha;
          mrow = mnew;
#pragma unroll
          for (int j = 0; j < 4; ++j) {
            float aj = __shfl(alpha, gq * 4 + j);   // alpha of q-row gq*4+j
#pragma unroll
            for (int df = 0; df < 4; ++df) yacc[df][j] *= aj;
          }
        }
        float msc = mrow * SC;
        float rs = 0.f;
#pragma unroll
        for (int f = 0; f < 8; ++f)
#pragma unroll
          for (int j = 0; j < 4; ++j) {
            float p = EXP2(__builtin_fmaf(s[f][j], SC, -msc));
            s[f][j] = p;
            rs += p;
          }
        rs += __shfl_xor(rs, 16);
        rs += __shfl_xor(rs, 32);
        lrow += rs;
      }
      // write P -> LDS as P[16 q][128 kv] (256B rows): lane owns row q=ln,
      // cols kv=f*16+gq*4..+3 -> one 8B write per f
#pragma unroll
      for (int f = 0; f < 8; ++f) {
        us4 pk;
#pragma unroll
        for (int j = 0; j < 4; ++j) pk[j] = f2h(s[f][j]);
        unsigned addr = pw + ln * 256 + ((f * 32 + gq * 8) ^ ((ln & 7) << 4));
        *(us4*)(lds + addr) = pk;
      }
      // PV: y[16 q][64 d] += P[16 q][128 kv] * V[128 kv][64 d]
#pragma unroll
      for (int st = 0; st < 4; ++st) {
        unsigned pc = (st * 64 + gq * 16) ^ ((ln & 7) << 4);
        short8 pa = *(const short8*)(lds + pw + ln * 256 + pc);
#pragma unroll
        for (int df = 0; df < 4; ++df) {
          unsigned row = df * 16 + ln;
          unsigned c0 = (st * 64 + gq * 16) ^ ((row & 7) << 4);
          short8 vb = *(const short8*)(lds + vb_ + row * 256 + c0);
          yacc[df] = mfma16(pa, vb, yacc[df]);
        }
      }
      __syncthreads();   // drain prefetch + protect buffers
      cur ^= 1;
    }

    // epilogue for this phase: y[b][t][h*64+d] fp16 (lrow lives at lane q; broadcast)
#pragma unroll
    for (int j = 0; j < 4; ++j) {
      float lj = __shfl(lrow, gq * 4 + j);
      float rl = 1.0f / lj;
      int tq = q0 + w * 16 + gq * 4 + j;
#pragma unroll
      for (int df = 0; df < 4; ++df) {
        int col = (bh & 15) * 64 + df * 16 + ln;
        size_t off = ((size_t)(bh >> 4) * 2048 + tq) * 1024 + col;
        yg[off] = f2h(yacc[df][j] * rl);
      }
    }
  }
}

extern "C" void kernel_launch(void* const* d_in, const int* in_sizes, int n_in,
                              void* d_out, int out_size, void* d_ws, size_t ws_size,
                              hipStream_t stream) {
  (void)in_sizes; (void)n_in; (void)out_size; (void)ws_size;
  const float* x     = (const float*)d_in[0];
  const float* wqkv  = (const float*)d_in[1];
  const float* wproj = (const float*)d_in[2];
  float* out = (float*)d_out;
  char* ws = (char*)d_ws;
  // ws layout (bytes)
  ushort_t* xb   = (ushort_t*)(ws);               // 16MB  (reused as y after QKV GEMM)
  ushort_t* wqkt = (ushort_t*)(ws + 16777216);    // 6MB
  ushort_t* wpt  = (ushort_t*)(ws + 23068672);    // 2MB
  ushort_t* qb_  = (ushort_t*)(ws + 25165824);    // 16MB [bh][t][d]
  ushort_t* kb_  = (ushort_t*)(ws + 41943040);    // 16MB [bh][t][d]
  ushort_t* vn   = (ushort_t*)(ws + 58720256);    // 16MB [bh][t][d]
  ushort_t* vt   = (ushort_t*)(ws + 75497472);    // 16MB [bh][d][t]
  ushort_t* yb   = xb;

  cast_f32_f16<<<2048, 256, 0, stream>>>((const float4*)x, (us4*)xb, 2097152);
  tcast<<<dim3(96, 32), 256, 0, stream>>>(wqkv, wqkt, 1024, 3072);
  tcast<<<dim3(32, 32), 256, 0, stream>>>(wproj, wpt, 1024, 1024);
  gemm128<0><<<dim3(24, 64), 256, 0, stream>>>(xb, wqkt, 1024, 3072, qb_, kb_, vn, nullptr);
  transpose_v<<<dim3(32, 64), 256, 0, stream>>>(vn, vt);
  attn_kernel<<<1024, 256, 0, stream>>>(qb_, kb_, vt, yb);
  gemm128<1><<<dim3(8, 64), 256, 0, stream>>>(yb, wpt, 1024, 1024, nullptr, nullptr, nullptr, out);
}

// Round 11
// 186.680 us; speedup vs baseline: 1.7251x; 1.0252x over previous
//
#include <hip/hip_runtime.h>
#include <stdint.h>

typedef unsigned short ushort_t;
typedef __attribute__((ext_vector_type(8))) short short8;
typedef __attribute__((ext_vector_type(8))) _Float16 half8;
typedef __attribute__((ext_vector_type(4))) float f32x4;
typedef __attribute__((ext_vector_type(4))) unsigned short us4;

#define AS1 __attribute__((address_space(1)))
#define AS3 __attribute__((address_space(3)))

#if __has_builtin(__builtin_amdgcn_exp2f)
#define EXP2(x) __builtin_amdgcn_exp2f(x)
#else
#define EXP2(x) exp2f(x)
#endif

// scores are multiplied by 8 (the reference's /scale bug); fold into exp2 base
#define SC 11.541560327111707f  // 8 * log2(e)

__device__ __forceinline__ ushort_t f2h(float f) {
  _Float16 h = (_Float16)f;   // v_cvt_f16_f32, RNE
  return __builtin_bit_cast(unsigned short, h);
}

__device__ __forceinline__ void gload16(const void* g, void* l) {
  __builtin_amdgcn_global_load_lds((AS1 const void*)g, (AS3 void*)l, 16, 0, 0);
}

__device__ __forceinline__ f32x4 mfma16(short8 a, short8 b, f32x4 c) {
  return __builtin_amdgcn_mfma_f32_16x16x32_f16(
      __builtin_bit_cast(half8, a), __builtin_bit_cast(half8, b), c, 0, 0, 0);
}

// ---------------- cast x fp32 -> fp16 ----------------
__global__ __launch_bounds__(256) void cast_f32_f16(const float4* __restrict__ in,
                                                    us4* __restrict__ out, int n4) {
  int i = blockIdx.x * 256 + threadIdx.x;
  int stride = gridDim.x * 256;
  for (; i < n4; i += stride) {
    float4 v = in[i];
    us4 o;
    o[0] = f2h(v.x); o[1] = f2h(v.y); o[2] = f2h(v.z); o[3] = f2h(v.w);
    out[i] = o;
  }
}

// ---------------- transpose-cast W [R][C] fp32 -> Wt [C][R] fp16 ----------------
__global__ __launch_bounds__(256) void tcast(const float* __restrict__ in,
                                             ushort_t* __restrict__ out, int R, int C) {
  __shared__ __align__(16) float lt[32][33];
  const int r0 = blockIdx.y * 32, c0 = blockIdx.x * 32;
  const int i = threadIdx.x;
  const int lr = i >> 3, lc = (i & 7) * 4;
  float4 v = *(const float4*)(in + (size_t)(r0 + lr) * C + c0 + lc);
  lt[lr][lc + 0] = v.x; lt[lr][lc + 1] = v.y; lt[lr][lc + 2] = v.z; lt[lr][lc + 3] = v.w;
  __syncthreads();
  const int oc = i >> 3;          // out row (a column c of in)
  const int orr = (i & 7) * 4;    // out col (row r of in)
  us4 o;
#pragma unroll
  for (int jj = 0; jj < 4; ++jj) o[jj] = f2h(lt[orr + jj][oc]);
  *(us4*)(out + (size_t)(c0 + oc) * R + r0 + orr) = o;
}

// ---------------- 128x128 fp16 GEMM, BK=64, A[M][K] x Bt[N][K] ----------------
// MODE 0: epilogue scatters Q,K into [bh][t][d] (fp16) and V TRANSPOSED into [bh][d][t]
// MODE 1: epilogue writes fp32 out[M][N]
template<int MODE>
__global__ __launch_bounds__(256) void gemm128(
    const ushort_t* __restrict__ A, const ushort_t* __restrict__ Bt, int K, int N,
    ushort_t* __restrict__ qo, ushort_t* __restrict__ ko, ushort_t* __restrict__ vo,
    float* __restrict__ outp)
{
  __shared__ __align__(16) unsigned char lds[32768];   // A tile 16K, B tile 16K
  const int tid = threadIdx.x;
  const int lane = tid & 63, w = tid >> 6;
  const int ln = lane & 15, gq = lane >> 4;
  const int wr = w >> 1, wc = w & 1;
  const int m0 = blockIdx.y * 128, n0 = blockIdx.x * 128;
  const size_t ldb = (size_t)K * 2;  // row bytes
  const unsigned char* ab = (const unsigned char*)A + (size_t)m0 * ldb;
  const unsigned char* bb = (const unsigned char*)Bt + (size_t)n0 * ldb;
  f32x4 acc[4][4] = {};
  const int nkt = K >> 6;
  for (int kb = 0; kb < nkt; ++kb) {
    const unsigned char* abk = ab + kb * 128;
    const unsigned char* bbk = bb + kb * 128;
#pragma unroll
    for (int e = 0; e < 4; ++e) {
      unsigned o = e * 4096 + tid * 16;
      unsigned r = o >> 7;
      unsigned c = (o & 127) ^ ((r & 7) << 4);   // pre-swizzled source
      gload16(abk + (size_t)r * ldb + c, lds + o);
      gload16(bbk + (size_t)r * ldb + c, lds + 16384 + o);
    }
    __syncthreads();
    short8 af[4][2], bf8[4][2];
#pragma unroll
    for (int mi = 0; mi < 4; ++mi) {
      unsigned row = wr * 64 + mi * 16 + ln;
      unsigned c0 = (gq * 16) ^ ((row & 7) << 4);
      af[mi][0] = *(const short8*)(lds + row * 128 + c0);
      af[mi][1] = *(const short8*)(lds + row * 128 + (c0 ^ 64));
    }
#pragma unroll
    for (int ni = 0; ni < 4; ++ni) {
      unsigned row = wc * 64 + ni * 16 + ln;
      unsigned c0 = (gq * 16) ^ ((row & 7) << 4);
      bf8[ni][0] = *(const short8*)(lds + 16384 + row * 128 + c0);
      bf8[ni][1] = *(const short8*)(lds + 16384 + row * 128 + (c0 ^ 64));
    }
#pragma unroll
    for (int mi = 0; mi < 4; ++mi)
#pragma unroll
      for (int ni = 0; ni < 4; ++ni) {
        acc[mi][ni] = mfma16(af[mi][0], bf8[ni][0], acc[mi][ni]);
        acc[mi][ni] = mfma16(af[mi][1], bf8[ni][1], acc[mi][ni]);
      }
    __syncthreads();
  }
  // epilogue: D layout col = lane&15, row = (lane>>4)*4 + j
  if (MODE == 0) {
#pragma unroll
    for (int mi = 0; mi < 4; ++mi)
#pragma unroll
      for (int ni = 0; ni < 4; ++ni) {
        int feat = n0 + wc * 64 + ni * 16 + ln;
        int sec = feat >> 10, cc = feat & 1023;   // sec is wave-uniform per (wc,ni)
        int hh = cc >> 6, dd = cc & 63;
        int tokbase = m0 + wr * 64 + mi * 16 + gq * 4;   // j=0 token (multiple of 4)
        int bh = (tokbase >> 11) * 16 + hh;
        int tloc = tokbase & 2047;
        if (sec == 2) {
          // V transposed: [bh][d][t], 4 consecutive tokens -> one 8B store
          us4 pk;
#pragma unroll
          for (int j = 0; j < 4; ++j) pk[j] = f2h(acc[mi][ni][j]);
          *(us4*)(vo + ((size_t)bh * 64 + dd) * 2048 + tloc) = pk;
        } else {
          ushort_t* dst = (sec == 0) ? qo : ko;
#pragma unroll
          for (int j = 0; j < 4; ++j) {
            size_t off = ((size_t)bh * 2048 + tloc + j) * 64 + dd;
            dst[off] = f2h(acc[mi][ni][j]);
          }
        }
      }
  } else {
#pragma unroll
    for (int mi = 0; mi < 4; ++mi)
#pragma unroll
      for (int ni = 0; ni < 4; ++ni)
#pragma unroll
        for (int j = 0; j < 4; ++j) {
          int token = m0 + wr * 64 + mi * 16 + gq * 4 + j;
          int feat  = n0 + wc * 64 + ni * 16 + ln;
          outp[(size_t)token * N + feat] = acc[mi][ni][j];
        }
  }
}

// ---------------- flash attention: causal pair-balanced, QBLK=64, KVBLK=64 ----------------
// Swapped QK^T (softmax lane-local, q = lane&15) + deferred rescale (THR=8 exp2-units)
// + setprio around MFMA clusters.
// LDS: K dbuf @0/8192, Vt dbuf @16384/24576, P per-wave @32768 + w*2048 (40960B -> 4 blocks/CU)
__global__ __launch_bounds__(256) void attn_kernel(const ushort_t* __restrict__ qg,
                                                   const ushort_t* __restrict__ kg,
                                                   const ushort_t* __restrict__ vtg,
                                                   ushort_t* __restrict__ yg) {
  __shared__ __align__(16) unsigned char lds[40960];
  const int n = blockIdx.x;                 // 0..1023
  const int xcd = n & 7, loc = n >> 3;      // XCD-grouped decode
  const int bh = xcd * 8 + (loc >> 4);      // 0..63; all 16 pair-blocks of a bh on one XCD
  const int pair = loc & 15;                // 0..15
  const int tid = threadIdx.x;
  const int lane = tid & 63, w = tid >> 6;
  const int ln = lane & 15, gq = lane >> 4;

  const unsigned char* kbase = (const unsigned char*)kg + (size_t)bh * 2048 * 128;
  const unsigned char* vbase = (const unsigned char*)vtg + (size_t)bh * 64 * 4096;
  const ushort_t* qg_bh = qg + (size_t)bh * 2048 * 64;
  const unsigned pw = 32768 + w * 2048;

  // stage kv tile t into buffer buf (K: 8KB contiguous; Vt: 64 rows x 128B, row stride 4KB)
  auto stage = [&](int buf, int t) {
    const unsigned char* kt = kbase + (size_t)t * 8192;
    const unsigned char* vt = vbase + t * 128;
#pragma unroll
    for (int e = 0; e < 2; ++e) {
      unsigned o = e * 4096 + tid * 16;
      unsigned r = o >> 7;
      unsigned c = (o & 127) ^ ((r & 7) << 4);
      gload16(kt + r * 128 + c, lds + buf * 8192 + o);
      gload16(vt + (size_t)r * 4096 + c, lds + 16384 + buf * 8192 + o);
    }
  };

  int cur = 0;
  for (int ph = 0; ph < 2; ++ph) {
    const int qt = (ph == 0) ? pair : 31 - pair;
    const int q0 = qt * 64;
    const int nt = qt + 1;

    // Q fragments: lane ln holds q-row (w*16+ln), k = st*32 + gq*8 + j
    const ushort_t* qrow = qg_bh + (size_t)(q0 + w * 16 + ln) * 64;
    short8 qa0 = *(const short8*)(qrow + gq * 8);
    short8 qa1 = *(const short8*)(qrow + 32 + gq * 8);

    f32x4 yacc[4] = {};
    float mrow = -3e38f, lrow = 0.f;   // lane-local state for q-row = w*16+ln

    stage(cur, 0);
    __syncthreads();

    for (int t = 0; t < nt; ++t) {
      if (t + 1 < nt) stage(cur ^ 1, t + 1);   // depth-1 prefetch (other buffer)
      const unsigned kb_ = cur * 8192;
      const unsigned vb_ = 16384 + cur * 8192;
      // swapped QK^T: S^T[kv][q] fragments; col=ln=q, row=gq*4+j (+f*16 = kv)
      f32x4 s[4];
      __builtin_amdgcn_s_setprio(1);
#pragma unroll
      for (int f = 0; f < 4; ++f) {
        unsigned row = f * 16 + ln;
        unsigned c0 = (gq * 16) ^ ((row & 7) << 4);
        short8 k0 = *(const short8*)(lds + kb_ + row * 128 + c0);
        short8 k1 = *(const short8*)(lds + kb_ + row * 128 + (c0 ^ 64));
        f32x4 z = {0.f, 0.f, 0.f, 0.f};
        z = mfma16(k0, qa0, z);
        s[f] = mfma16(k1, qa1, z);
      }
      __builtin_amdgcn_s_setprio(0);
      if (t == nt - 1) {   // diagonal tile (kv0 == q0): mask kv > q in local coords
        int qloc = w * 16 + ln;
#pragma unroll
        for (int f = 0; f < 4; ++f) {
          int kvb = f * 16 + gq * 4;
#pragma unroll
          for (int j = 0; j < 4; ++j)
            if (kvb + j > qloc) s[f][j] = -3e38f;
        }
      }
      // online softmax: lane holds 16 scores all for q = w*16+ln
      // deferred rescale (THR=8 exp2-units) + fma-folded exp2
      {
        float rm = s[0][0];
#pragma unroll
        for (int f = 0; f < 4; ++f)
#pragma unroll
          for (int j = 0; j < 4; ++j) rm = fmaxf(rm, s[f][j]);
        rm = fmaxf(rm, __shfl_xor(rm, 16));
        rm = fmaxf(rm, __shfl_xor(rm, 32));
        if (__any((rm - mrow) * SC > 8.0f)) {
          float mnew = fmaxf(mrow, rm);
          float alpha = EXP2((mrow - mnew) * SC);
          lrow *= alpha;
          mrow = mnew;
#pragma unroll
          for (int j = 0; j < 4; ++j) {
            float aj = __shfl(alpha, gq * 4 + j);   // alpha of q-row gq*4+j
#pragma unroll
            for (int df = 0; df < 4; ++df) yacc[df][j] *= aj;
          }
        }
        float msc = mrow * SC;
        float rs = 0.f;
#pragma unroll
        for (int f = 0; f < 4; ++f)
#pragma unroll
          for (int j = 0; j < 4; ++j) {
            float p = EXP2(__builtin_fmaf(s[f][j], SC, -msc));
            s[f][j] = p;
            rs += p;
          }
        rs += __shfl_xor(rs, 16);
        rs += __shfl_xor(rs, 32);
        lrow += rs;
      }
      // write P -> LDS as P[16 q][64 kv]: lane owns row q=ln, cols kv=f*16+gq*4..+3
#pragma unroll
      for (int f = 0; f < 4; ++f) {
        us4 pk;
#pragma unroll
        for (int j = 0; j < 4; ++j) pk[j] = f2h(s[f][j]);
        unsigned addr = (pw + ln * 128 + (f * 16 + gq * 4) * 2) ^ ((ln & 7) << 4);
        *(us4*)(lds + addr) = pk;
      }
      // PV: y[16 q][64 d] += P[16 q][64 kv] * V[64 kv][64 d]
      __builtin_amdgcn_s_setprio(1);
#pragma unroll
      for (int st = 0; st < 2; ++st) {
        unsigned pc = (st * 64 + gq * 16) ^ ((ln & 7) << 4);
        short8 pa = *(const short8*)(lds + pw + ln * 128 + pc);
#pragma unroll
        for (int df = 0; df < 4; ++df) {
          unsigned row = df * 16 + ln;
          unsigned c0 = (st * 64 + gq * 16) ^ ((row & 7) << 4);
          short8 vb = *(const short8*)(lds + vb_ + row * 128 + c0);
          yacc[df] = mfma16(pa, vb, yacc[df]);
        }
      }
      __builtin_amdgcn_s_setprio(0);
      __syncthreads();   // drain prefetch + protect buffers
      cur ^= 1;
    }

    // epilogue for this phase: y[b][t][h*64+d] fp16 (lrow lives at lane q; broadcast)
#pragma unroll
    for (int j = 0; j < 4; ++j) {
      float lj = __shfl(lrow, gq * 4 + j);
      float rl = 1.0f / lj;
      int tq = q0 + w * 16 + gq * 4 + j;
#pragma unroll
      for (int df = 0; df < 4; ++df) {
        int col = (bh & 15) * 64 + df * 16 + ln;
        size_t off = ((size_t)(bh >> 4) * 2048 + tq) * 1024 + col;
        yg[off] = f2h(yacc[df][j] * rl);
      }
    }
  }
}

extern "C" void kernel_launch(void* const* d_in, const int* in_sizes, int n_in,
                              void* d_out, int out_size, void* d_ws, size_t ws_size,
                              hipStream_t stream) {
  (void)in_sizes; (void)n_in; (void)out_size; (void)ws_size;
  const float* x     = (const float*)d_in[0];
  const float* wqkv  = (const float*)d_in[1];
  const float* wproj = (const float*)d_in[2];
  float* out = (float*)d_out;
  char* ws = (char*)d_ws;
  // ws layout (bytes)
  ushort_t* xb   = (ushort_t*)(ws);               // 16MB  (reused as y after QKV GEMM)
  ushort_t* wqkt = (ushort_t*)(ws + 16777216);    // 6MB
  ushort_t* wpt  = (ushort_t*)(ws + 23068672);    // 2MB
  ushort_t* qb_  = (ushort_t*)(ws + 25165824);    // 16MB [bh][t][d]
  ushort_t* kb_  = (ushort_t*)(ws + 41943040);    // 16MB [bh][t][d]
  ushort_t* vt   = (ushort_t*)(ws + 75497472);    // 16MB [bh][d][t] (written by gemm<0>)
  ushort_t* yb   = xb;

  cast_f32_f16<<<2048, 256, 0, stream>>>((const float4*)x, (us4*)xb, 2097152);
  tcast<<<dim3(96, 32), 256, 0, stream>>>(wqkv, wqkt, 1024, 3072);
  tcast<<<dim3(32, 32), 256, 0, stream>>>(wproj, wpt, 1024, 1024);
  gemm128<0><<<dim3(24, 64), 256, 0, stream>>>(xb, wqkt, 1024, 3072, qb_, kb_, vt, nullptr);
  attn_kernel<<<1024, 256, 0, stream>>>(qb_, kb_, vt, yb);
  gemm128<1><<<dim3(8, 64), 256, 0, stream>>>(yb, wpt, 1024, 1024, nullptr, nullptr, nullptr, out);
}